// Round 9
// baseline (216.145 us; speedup 1.0000x reference)
//
#include <hip/hip_runtime.h>
#include <cstdint>
#include <cmath>

// ---- d_ws layout (4-byte words) ----
// Thresholds are stored as negthr = -(thr+1):  pc <= thr  <=>  (pc + negthr) < 0
#define OFF_W1   0      // 32  u32: conv1 weight bits (27 bits: c*9+dy*3+dx)
#define OFF_T1   32     // 32  i32: conv1 negthr
#define OFF_W2   64     // 288 u32: conv2 weight bits [o][k] over 32 in-ch
#define OFF_T2   352    // 32  i32: conv2 negthr
#define OFF_W3   384    // 576 u32: conv3 weight bits [o][k]
#define OFF_T3   960    // 64  i32: conv3 negthr
#define OFF_WFC1 1024   // 256 u32: fc1 weight bits, 2 words per output (64 bits)
#define OFF_A4   1280   // 128 f32
#define OFF_C4   1408   // 128 f32
#define OFF_WF2  1536   // 256 f32: w_fc2 [2][128]
#define OFF_WF3  1792   // 512 f32: w_fc3 [4][128]
#define OFF_BN5  2304   // 4 f32
#define OFF_BN6  2308   // 8 f32
#define OFF_BM   4096   // B*46 u32: per-image 1452-bit sign bitmaps (46 words)

__device__ __forceinline__ int thr_neg(double nterms, double g, double b, double m, double v) {
    double inv = g / sqrt(v + 1e-5);
    double t = m - b / inv;                   // bit=1  <=>  c >= t   (inv > 0)
    double thr = floor((nterms - t) * 0.5);   // c = nterms - 2*pc  =>  pc <= thr
    if (thr < -2147000000.0) thr = -2147000000.0;
    if (thr >  2147000000.0) thr =  2147000000.0;
    return -((int)thr + 1);                   // sign(pc + negthr) == (pc <= thr)
}

// 5 blocks x 256 threads. Coalesced global->LDS staging, then bit-pack from LDS.
__global__ void k_prep(const float* __restrict__ w1, const float* __restrict__ w2,
                       const float* __restrict__ w3, const float* __restrict__ wfc1,
                       const float* __restrict__ wfc2, const float* __restrict__ wfc3,
                       const float* __restrict__ bn1, const float* __restrict__ bn2,
                       const float* __restrict__ bn3, const float* __restrict__ bn4,
                       const float* __restrict__ bn5, const float* __restrict__ bn6,
                       unsigned int* __restrict__ ws) {
    __shared__ float stage[9216];
    int t = threadIdx.x;
    int blk = blockIdx.x;
    float* wsf = (float*)ws;
    int*   wsi = (int*)ws;

    if (blk == 0) {
        for (int i = t; i < 864; i += 256) stage[i] = w1[i];
        __syncthreads();
        if (t < 32) {
            unsigned int bits = 0;
            for (int j = 0; j < 27; ++j) bits |= (stage[t*27+j] >= 0.f ? 1u : 0u) << j;
            ws[OFF_W1 + t] = bits;
            wsi[OFF_T1 + t] = thr_neg(27.0,  bn1[t], bn1[32+t], bn1[64+t], bn1[96+t]);
            wsi[OFF_T2 + t] = thr_neg(288.0, bn2[t], bn2[32+t], bn2[64+t], bn2[96+t]);
        }
        for (int i = t; i < 256; i += 256) wsf[OFF_WF2 + i] = wfc2[i];
        for (int i = t; i < 512; i += 256) wsf[OFF_WF3 + i] = wfc3[i];
        if (t < 2) {
            float g = bn5[t], b = bn5[2+t], m = bn5[4+t], v = bn5[6+t];
            float inv = g / sqrtf(v + 1e-5f);
            wsf[OFF_BN5 + t]     = inv;
            wsf[OFF_BN5 + 2 + t] = b - m * inv;
        }
        if (t >= 4 && t < 8) {
            int j = t - 4;
            float g = bn6[j], b = bn6[4+j], m = bn6[8+j], v = bn6[12+j];
            float inv = g / sqrtf(v + 1e-5f);
            wsf[OFF_BN6 + j]     = inv;
            wsf[OFF_BN6 + 4 + j] = b - m * inv;
        }
    } else if (blk == 1) {
        for (int i = t; i < 9216; i += 256) stage[i] = w2[i];
        __syncthreads();
        for (int idx = t; idx < 288; idx += 256) {
            int o = idx / 9, k = idx - o*9;
            unsigned int bits = 0;
            for (int i = 0; i < 32; ++i)
                bits |= (stage[(o*32+i)*9 + k] >= 0.f ? 1u : 0u) << i;
            ws[OFF_W2 + idx] = bits;
        }
    } else if (blk == 2 || blk == 3) {
        int base = (blk - 2) * 9216;
        for (int i = t; i < 9216; i += 256) stage[i] = w3[base + i];
        __syncthreads();
        for (int idx = t; idx < 288; idx += 256) {
            int o = idx / 9, k = idx - o*9;
            unsigned int bits = 0;
            for (int i = 0; i < 32; ++i)
                bits |= (stage[(o*32+i)*9 + k] >= 0.f ? 1u : 0u) << i;
            ws[OFF_W3 + base/32 + idx] = bits;   // base/32 = 0 or 288
        }
    } else {
        for (int i = t; i < 8192; i += 256) stage[i] = wfc1[i];
        __syncthreads();
        if (t < 128) {
            unsigned int lo = 0, hi = 0;
            for (int j = 0; j < 32; ++j) lo |= (stage[t*64+j]    >= 0.f ? 1u : 0u) << j;
            for (int j = 0; j < 32; ++j) hi |= (stage[t*64+32+j] >= 0.f ? 1u : 0u) << j;
            ws[OFF_WFC1 + 2*t]     = lo;
            ws[OFF_WFC1 + 2*t + 1] = hi;
            float g = bn4[t], b = bn4[128+t], m = bn4[256+t], v = bn4[384+t];
            float inv = g / sqrtf(v + 1e-5f);
            wsf[OFF_A4 + t] = -2.f * inv;                 // c = 64 - 2*pc
            wsf[OFF_C4 + t] = (64.f - m) * inv + b;
        }
        if (t >= 128 && t < 192) {
            int j = t - 128;
            wsi[OFF_T3 + j] = thr_neg(288.0, bn3[j], bn3[64+j], bn3[128+j], bn3[192+j]);
        }
    }
}

// Streams the 95MB input ONCE at pure-bandwidth pace and emits 46-word sign
// bitmaps per image (3MB). Decouples the HBM/L3 input burst from k_main.
__global__ __launch_bounds__(256) void k_extract(const float* __restrict__ x,
                                                 unsigned int* __restrict__ bm,
                                                 int B) {
    const int tid = threadIdx.x & 63;
    const int wid = threadIdx.x >> 6;
    const int b   = blockIdx.x * 4 + wid;
    if (b >= B) return;
    const unsigned int base = (unsigned int)b * 1452u;
    const unsigned int last = (unsigned int)B * 1452u - 1u;
    unsigned int keep = 0;
    #pragma unroll 1
    for (int c = 0; c < 3; ++c) {
        const int kb = c * 8, kn = (c == 2) ? 7 : 8;
        float v[8];
        #pragma unroll
        for (int k = 0; k < 8; ++k)
            if (k < kn) {
                unsigned int idx = base + (unsigned int)(kb + k) * 64u + (unsigned int)tid;
                if (idx > last) idx = last;   // tail guard (junk bits never read)
                v[k] = x[idx];
            }
        #pragma unroll
        for (int k = 0; k < 8; ++k)
            if (k < kn) {
                unsigned long long m = __ballot(v[k] >= 0.f);
                int w2k = (kb + k) * 2;
                if (tid == w2k)     keep = (unsigned int)m;
                if (tid == w2k + 1) keep = (unsigned int)(m >> 32);
            }
    }
    if (tid < 46) bm[(size_t)b * 46 + tid] = keep;
}

// R4 structure (best measured: 67.3us, VALUBusy 76%, 2-cohort grid): 1 image
// per wave, 4 waves/block, wave-private LDS slices, wave_barrier fences.
// Only change: input pack stage reads the precomputed 46-word bitmap (2 global
// loads' worth) instead of streaming 5.8KB of floats per image.
#define WSTRIDE 584   // 66 + 400 + 100 + 16, padded to even
#define AB31(a,b) __builtin_amdgcn_alignbit(a, b, 31)
__global__ __launch_bounds__(256, 8) void k_main(const float* __restrict__ x,
                                                 const unsigned int* __restrict__ ws,
                                                 float* __restrict__ out, int B,
                                                 int use_bm) {
    __shared__ unsigned int s_u[4 * WSTRIDE];

    const int tid = threadIdx.x & 63;
    const int wid = threadIdx.x >> 6;
    const int b   = blockIdx.x * 4 + wid;
    if (b >= B) return;   // wave-uniform exit; no cross-wave deps anywhere
    const float* wsf = (const float*)ws;
    const int*   wsi = (const int*)ws;

    unsigned int* in   = s_u + wid * WSTRIDE;   // [66]
    unsigned int* c1   = in + 66;               // [400]
    unsigned int* pb1  = c1 + 400;              // [100]
    unsigned int* pb2  = pb1 + 100;             // [16]

    // ---- obtain the image's 1452-bit sign string (46 u32) into c1[0..45] ----
    if (use_bm) {
        if (tid < 46) c1[tid] = ws[OFF_BM + (size_t)b * 46 + tid];
    } else {
        // fallback: in-kernel ballot pack (R8-validated)
        unsigned long long* bal = (unsigned long long*)c1;
        const unsigned int base = (unsigned int)b * 1452u;
        const unsigned int last = (unsigned int)B * 1452u - 1u;
        #pragma unroll 1
        for (int c = 0; c < 3; ++c) {
            const int kb = c * 8, kn = (c == 2) ? 7 : 8;
            float v[8];
            #pragma unroll
            for (int k = 0; k < 8; ++k)
                if (k < kn) {
                    unsigned int idx = base + (unsigned int)(kb + k) * 64u + (unsigned int)tid;
                    if (idx > last) idx = last;
                    v[k] = x[idx];
                }
            #pragma unroll
            for (int k = 0; k < 8; ++k)
                if (k < kn) {
                    unsigned long long m = __ballot(v[k] >= 0.f);
                    if (tid == 0) bal[kb + k] = m;
                }
        }
    }
    __builtin_amdgcn_wave_barrier();

    // ---- row words = 22-bit windows of the sign string ----
    for (int r = tid; r < 66; r += 64) {
        int bitpos = r * 22;
        int wi = bitpos >> 5, sh = bitpos & 31;
        in[r] = __builtin_amdgcn_alignbit(c1[wi + 1], c1[wi], sh);
    }
    __builtin_amdgcn_wave_barrier();

    // ---- conv1 + BN sign: 3 VALU per (pos,och): xor, bcnt(acc=negthr), alignbit ----
    for (int pos = tid; pos < 400; pos += 64) {
        int y = pos / 20, xx = pos - y*20;
        unsigned int g = 0;
        #pragma unroll
        for (int c = 0; c < 3; ++c)
            #pragma unroll
            for (int dy = 0; dy < 3; ++dy)
                g |= ((in[c*22 + y + dy] >> xx) & 7u) << (c*9 + dy*3);
        unsigned int word = 0;
        #pragma unroll
        for (int o = 31; o >= 0; --o) {
            unsigned int s = (unsigned int)(__popc(g ^ ws[OFF_W1 + o]) + wsi[OFF_T1 + o]);
            word = AB31(word, s);  // word=(word<<1)|(s>>31)
        }
        c1[pos] = word;
    }
    __builtin_amdgcn_wave_barrier();

    // ---- maxpool1 == OR of sign bits ----
    for (int p = tid; p < 100; p += 64) {
        int py = p / 10, px = p - py*10;
        int base = (2*py)*20 + 2*px;
        pb1[p] = c1[base] | c1[base+1] | c1[base+20] | c1[base+21];
    }
    __builtin_amdgcn_wave_barrier();

    // ---- conv2 + BN sign + pool2 (lane = one of 8x8 positions) ----
    {
        int y = tid >> 3, xx = tid & 7;
        unsigned int in9[9];
        #pragma unroll
        for (int dy = 0; dy < 3; ++dy)
            #pragma unroll
            for (int dx = 0; dx < 3; ++dx)
                in9[dy*3+dx] = pb1[(y+dy)*10 + xx + dx];
        unsigned int word = 0;
        #pragma unroll
        for (int o = 31; o >= 0; --o) {
            int s = wsi[OFF_T2 + o];
            #pragma unroll
            for (int k = 0; k < 9; ++k)
                s += __popc(in9[k] ^ ws[OFF_W2 + o*9 + k]);
            word = AB31(word, (unsigned int)s);
        }
        word |= __shfl_xor(word, 1);   // pool across x pairs
        word |= __shfl_xor(word, 8);   // pool across y pairs
        if ((tid & 9) == 0)            // x even, y even
            pb2[(y>>1)*4 + (xx>>1)] = word;
    }
    __builtin_amdgcn_wave_barrier();

    // ---- conv3 + BN sign + pool3 -> 64-bit feature via ballot (lane = och) ----
    unsigned long long b3 = 0;
    {
        unsigned int bb[16];
        #pragma unroll
        for (int i = 0; i < 16; ++i) bb[i] = pb2[i];
        unsigned int w3r[9];
        #pragma unroll
        for (int k = 0; k < 9; ++k) w3r[k] = ws[OFF_W3 + tid*9 + k];
        int negt = wsi[OFF_T3 + tid];
        unsigned int oracc = 0;
        #pragma unroll
        for (int py = 0; py < 2; ++py)
            #pragma unroll
            for (int px = 0; px < 2; ++px) {
                int s = negt;
                #pragma unroll
                for (int dy = 0; dy < 3; ++dy)
                    #pragma unroll
                    for (int dx = 0; dx < 3; ++dx)
                        s += __popc(bb[(py+dy)*4 + px + dx] ^ w3r[dy*3+dx]);
                oracc |= (unsigned int)s;
            }
        b3 = __ballot((int)oracc < 0);
    }

    // ---- fc1 in registers (outputs tid, tid+64 consumed by the same lane) ----
    float h0, h1;
    {
        const unsigned long long* wfc1b = (const unsigned long long*)(ws + OFF_WFC1);
        int pc0 = __popcll(b3 ^ wfc1b[tid]);
        int pc1 = __popcll(b3 ^ wfc1b[tid + 64]);
        float p0 = fmaf((float)pc0, wsf[OFF_A4 + tid],      wsf[OFF_C4 + tid]);
        float p1 = fmaf((float)pc1, wsf[OFF_A4 + tid + 64], wsf[OFF_C4 + tid + 64]);
        h0 = fminf(1.f, fmaxf(-1.f, p0));
        h1 = fminf(1.f, fmaxf(-1.f, p1));
    }

    // ---- fc2 (softmax) / fc3 (BN) ----
    {
        float part[6];
        #pragma unroll
        for (int j = 0; j < 2; ++j)
            part[j] = h0 * wsf[OFF_WF2 + j*128 + tid] + h1 * wsf[OFF_WF2 + j*128 + 64 + tid];
        #pragma unroll
        for (int j = 0; j < 4; ++j)
            part[2+j] = h0 * wsf[OFF_WF3 + j*128 + tid] + h1 * wsf[OFF_WF3 + j*128 + 64 + tid];
        #pragma unroll
        for (int off = 32; off; off >>= 1) {
            #pragma unroll
            for (int j = 0; j < 6; ++j)
                part[j] += __shfl_xor(part[j], off);
        }
        if (tid < 6) {
            if (tid < 2) {
                float y0 = part[0]*wsf[OFF_BN5+0] + wsf[OFF_BN5+2];
                float y1 = part[1]*wsf[OFF_BN5+1] + wsf[OFF_BN5+3];
                float mx = fmaxf(y0, y1);
                float e0 = expf(y0 - mx), e1 = expf(y1 - mx);
                float r  = 1.f / (e0 + e1);
                out[(size_t)b*2 + tid] = (tid == 0 ? e0 : e1) * r;
            } else {
                int j = tid - 2;
                out[(size_t)B*2 + (size_t)b*4 + j] = part[2+j]*wsf[OFF_BN6+j] + wsf[OFF_BN6+4+j];
            }
        }
    }
}

extern "C" void kernel_launch(void* const* d_in, const int* in_sizes, int n_in,
                              void* d_out, int out_size, void* d_ws, size_t ws_size,
                              hipStream_t stream) {
    const float* x    = (const float*)d_in[0];
    const float* w1   = (const float*)d_in[1];
    const float* w2   = (const float*)d_in[2];
    const float* w3   = (const float*)d_in[3];
    const float* wfc1 = (const float*)d_in[4];
    const float* wfc2 = (const float*)d_in[5];
    const float* wfc3 = (const float*)d_in[6];
    const float* bn1  = (const float*)d_in[7];
    const float* bn2  = (const float*)d_in[8];
    const float* bn3  = (const float*)d_in[9];
    const float* bn4  = (const float*)d_in[10];
    const float* bn5  = (const float*)d_in[11];
    const float* bn6  = (const float*)d_in[12];
    unsigned int* ws  = (unsigned int*)d_ws;
    float* out        = (float*)d_out;
    int B = in_sizes[0] / 1452;   // 3*22*22

    size_t need = (size_t)OFF_BM * 4 + (size_t)B * 46 * 4;
    int use_bm = (ws_size >= need) ? 1 : 0;

    if (use_bm)
        k_extract<<<(B + 3) / 4, 256, 0, stream>>>(x, ws + OFF_BM, B);
    k_prep<<<5, 256, 0, stream>>>(w1, w2, w3, wfc1, wfc2, wfc3,
                                  bn1, bn2, bn3, bn4, bn5, bn6, ws);
    k_main<<<(B + 3) / 4, 256, 0, stream>>>(x, ws, out, B, use_bm);
}